// Round 6
// baseline (446.756 us; speedup 1.0000x reference)
//
#include <hip/hip_runtime.h>

#define NN 20000
#define NPAD 20064  // >= 626*32 = 20032 rows covered by GEMM grid

typedef _Float16 half8 __attribute__((ext_vector_type(8)));
typedef _Float16 half2v __attribute__((ext_vector_type(2)));
typedef float floatx4 __attribute__((ext_vector_type(4)));

#define MFMA16(a, b, c) __builtin_amdgcn_mfma_f32_16x16x32_f16((a), (b), (c), 0, 0, 0)

// ---------------- B-spline basis (grid [-1,1], G=4, order 3, NB=7) ----------------
__device__ __forceinline__ void bspline7(float x, float b[7]) {
  float t[10];
#pragma unroll
  for (int i = 0; i < 10; ++i) {
    float g = -2.5f + 0.5f * (float)i;
    t[i] = (x >= g && x < g + 0.5f) ? 1.0f : 0.0f;
  }
#pragma unroll
  for (int i = 0; i < 9; ++i) {  // k=1, denom 0.5
    float g = -2.5f + 0.5f * (float)i;
    t[i] = ((x - g) * t[i] + (g + 1.0f - x) * t[i + 1]) * 2.0f;
  }
#pragma unroll
  for (int i = 0; i < 8; ++i) {  // k=2, denom 1.0
    float g = -2.5f + 0.5f * (float)i;
    t[i] = ((x - g) * t[i] + (g + 1.5f - x) * t[i + 1]);
  }
#pragma unroll
  for (int i = 0; i < 7; ++i) {  // k=3, denom 1.5
    float g = -2.5f + 0.5f * (float)i;
    b[i] = ((x - g) * t[i] + (g + 2.0f - x) * t[i + 1]) * (1.0f / 1.5f);
  }
}

__device__ __forceinline__ float silu_f(float x) {
  return x * (1.0f / (1.0f + __expf(-x)));
}

// ---------------- feature build: X (f32 row-major) -> F fp16 [row][i][j=0..7] ----------------
__global__ void fb_kernel(const float* __restrict__ X, const float* __restrict__ ss,
                          _Float16* __restrict__ F, int has_bn) {
  int idx = blockIdx.x * 256 + threadIdx.x;  // NN*128 = 2,560,000
  if (idx >= NN * 128) return;
  int c = idx & 127;
  float x = X[idx];
  if (has_bn) x = x * ss[c] + ss[128 + c];
  float b[7];
  bspline7(x, b);
  half8 hv;
  hv[0] = (_Float16)silu_f(x);
#pragma unroll
  for (int k = 0; k < 7; ++k) hv[k + 1] = (_Float16)b[k];
  *(half8*)(F + (size_t)idx * 8) = hv;
}

// ---------------- merged weight pack (MFMA B-fragment order) ----------------
__global__ void packw_all(const float* __restrict__ Wb0, const float* __restrict__ Ws0,
                          const float* __restrict__ Wb1, const float* __restrict__ Ws1,
                          const float* __restrict__ WbO, const float* __restrict__ WsO,
                          _Float16* __restrict__ WPA0, _Float16* __restrict__ WPA1,
                          _Float16* __restrict__ WPC) {
  int bid = blockIdx.x;
  if (bid < 1536) {
    int s = (bid >= 768) ? 1 : 0;
    int idx = (bid - s * 768) * 256 + threadIdx.x;  // 32*12*64*8 = 196608
    if (idx >= 196608) return;
    const float* Wb = s ? Wb1 : Wb0;
    const float* Wsp = s ? Ws1 : Ws0;
    _Float16* WP = s ? WPA1 : WPA0;
    int jj = idx & 7;
    int lane = (idx >> 3) & 63;
    int u = idx >> 9;  // ks*12 + cb
    int cb = u % 12, ks = u / 12;
    int i = ks * 4 + (lane >> 4);
    int orow = lane & 15;
    float v = 0.0f;
    if (cb < 8) {
      int o = cb * 16 + orow;
      v = (jj == 0) ? Wb[(size_t)o * 128 + i] : Wsp[(size_t)o * 896 + i * 7 + (jj - 1)];
    } else {
      int o = (cb - 8) * 16 + orow;
      if (o < 40)
        v = (jj == 0) ? WbO[(size_t)o * 384 + s * 128 + i]
                      : WsO[(size_t)o * 2688 + s * 896 + i * 7 + (jj - 1)];
    }
    WP[idx] = (_Float16)v;
  } else {
    int idx = (bid - 1536) * 256 + threadIdx.x;  // 32*4*64*8 = 65536
    if (idx >= 65536) return;
    int jj = idx & 7;
    int lane = (idx >> 3) & 63;
    int u = idx >> 9;
    int cb = u & 3, ks = u >> 2;
    int i = ks * 4 + (lane >> 4);
    int o = cb * 16 + (lane & 15);
    float v = 0.0f;
    if (o < 40)
      v = (jj == 0) ? WbO[(size_t)o * 384 + 2 * 128 + i]
                    : WsO[(size_t)o * 2688 + 2 * 896 + i * 7 + (jj - 1)];
    WPC[idx] = (_Float16)v;
  }
}

// ---------------- graph meta ----------------
__global__ void count_deg(const int* __restrict__ dst, int* __restrict__ degE, int E) {
  int e = blockIdx.x * 256 + threadIdx.x;
  if (e < E) atomicAdd(&degE[dst[e]], 1);
}

__global__ void build_meta2(const int* __restrict__ degE, int* __restrict__ rowptr,
                            int* __restrict__ cursor, float* __restrict__ dinv, int n) {
  __shared__ int wsum[16];
  int tid = threadIdx.x, lane = tid & 63, wid = tid >> 6;
  int i0 = tid * 20;
  int d[20];
  int s = 0;
#pragma unroll
  for (int j = 0; j < 20; ++j) {
    int i = i0 + j;
    int v = (i < n) ? degE[i] : 0;
    d[j] = v;
    s += v;
    if (i < n) dinv[i] = rsqrtf((float)(v + 1));  // +1 self loop
  }
  int val = s;
#pragma unroll
  for (int off = 1; off < 64; off <<= 1) {
    int t = __shfl_up(val, off);
    if (lane >= off) val += t;
  }
  if (lane == 63) wsum[wid] = val;
  __syncthreads();
  if (wid == 0) {
    int wv = (lane < 16) ? wsum[lane] : 0;
#pragma unroll
    for (int off = 1; off < 16; off <<= 1) {
      int t = __shfl_up(wv, off);
      if (lane >= off) wv += t;
    }
    if (lane < 16) wsum[lane] = wv;
  }
  __syncthreads();
  int base = (wid ? wsum[wid - 1] : 0) + val - s;
  if (tid == 0) rowptr[0] = 0;
#pragma unroll
  for (int j = 0; j < 20; ++j) {
    int i = i0 + j;
    if (i < n) {
      cursor[i] = base;
      rowptr[i + 1] = base + d[j];
      base += d[j];
    }
  }
}

__global__ void fill_csr(const int* __restrict__ src, const int* __restrict__ dst,
                         int* __restrict__ cursor, int* __restrict__ csr, int E) {
  int e = blockIdx.x * 256 + threadIdx.x;
  if (e < E) {
    int p = atomicAdd(&cursor[dst[e]], 1);
    csr[p] = src[e];
  }
}

// ---------------- GEMM A: F(K=1024) x [W_layer(128) | W_out_chunk(64)] ----------------
// 512 threads = 8 waves: rg = wid&1 (16 rows), cg = wid>>1 (3 cb). 3 MFMA/iter.
// Depth-1 register pipeline with sched_barrier fences. A out in fp16, P in f32.
__global__ __launch_bounds__(512) void gemmA4(const _Float16* __restrict__ F,
                                              const _Float16* __restrict__ WP,
                                              _Float16* __restrict__ A, float* __restrict__ P) {
  int lane = threadIdx.x & 63, wid = threadIdx.x >> 6;
  int rg = wid & 1, cg = wid >> 1;
  int row0 = blockIdx.x * 32 + rg * 16;
  const _Float16* Fr = F + ((size_t)(row0 + (lane & 15)) * 128 + (lane >> 4)) * 8;
  const _Float16* Bp = WP + ((size_t)(cg * 3) * 64 + lane) * 8;
  floatx4 acc0 = {}, acc1 = {}, acc2 = {};
  half8 a = *(const half8*)(Fr);
  half8 b0 = *(const half8*)(Bp);
  half8 b1 = *(const half8*)(Bp + 512);
  half8 b2 = *(const half8*)(Bp + 1024);
#pragma unroll 2
  for (int ks = 0; ks < 32; ++ks) {
    // prefetch ks+1 (buffers padded so ks=31 prefetch is in-bounds)
    half8 an = *(const half8*)(Fr + (size_t)(ks + 1) * 32);
    const _Float16* bn = Bp + (size_t)(ks + 1) * 6144;
    half8 b0n = *(const half8*)(bn);
    half8 b1n = *(const half8*)(bn + 512);
    half8 b2n = *(const half8*)(bn + 1024);
    __builtin_amdgcn_sched_barrier(0);
    acc0 = MFMA16(a, b0, acc0);
    acc1 = MFMA16(a, b1, acc1);
    acc2 = MFMA16(a, b2, acc2);
    __builtin_amdgcn_sched_barrier(0);
    a = an; b0 = b0n; b1 = b1n; b2 = b2n;
  }
  int oc = lane & 15;
  int r0 = row0 + (lane >> 4) * 4;
  floatx4 accs[3] = {acc0, acc1, acc2};
#pragma unroll
  for (int q = 0; q < 3; ++q) {
    int cb = cg * 3 + q;
    if (cb < 8) {
#pragma unroll
      for (int t = 0; t < 4; ++t)
        A[(size_t)(r0 + t) * 128 + cb * 16 + oc] = (_Float16)accs[q][t];
    } else {
#pragma unroll
      for (int t = 0; t < 4; ++t) P[(size_t)(r0 + t) * 64 + (cb - 8) * 16 + oc] = accs[q][t];
    }
  }
}

// final chunk: F(h2 feats) x W_out_chunk2 + P0 + P1 -> C fp16
// 512 threads = 8 waves: rg = wid&1 (16 rows), cg = wid>>1 (1 cb). 1 MFMA/iter.
__global__ __launch_bounds__(512) void gemmC4(const _Float16* __restrict__ F,
                                              const _Float16* __restrict__ WP,
                                              const float* __restrict__ P0,
                                              const float* __restrict__ P1,
                                              _Float16* __restrict__ C) {
  int lane = threadIdx.x & 63, wid = threadIdx.x >> 6;
  int rg = wid & 1, cg = wid >> 1;
  int row0 = blockIdx.x * 32 + rg * 16;
  const _Float16* Fr = F + ((size_t)(row0 + (lane & 15)) * 128 + (lane >> 4)) * 8;
  const _Float16* Bp = WP + ((size_t)cg * 64 + lane) * 8;
  floatx4 acc = {};
  half8 a = *(const half8*)(Fr);
  half8 b = *(const half8*)(Bp);
#pragma unroll 2
  for (int ks = 0; ks < 32; ++ks) {
    half8 an = *(const half8*)(Fr + (size_t)(ks + 1) * 32);
    half8 bn = *(const half8*)(Bp + (size_t)(ks + 1) * 2048);
    __builtin_amdgcn_sched_barrier(0);
    acc = MFMA16(a, b, acc);
    __builtin_amdgcn_sched_barrier(0);
    a = an; b = bn;
  }
  int oc = lane & 15;
  int r0 = row0 + (lane >> 4) * 4;
#pragma unroll
  for (int t = 0; t < 4; ++t) {
    size_t idx = (size_t)(r0 + t) * 64 + cg * 16 + oc;
    C[idx] = (_Float16)(acc[t] + P0[idx] + P1[idx]);
  }
}

// ---------------- aggregation: wave per node, fp16 gather, depth-2 pipeline ----------------
__global__ __launch_bounds__(256) void aggregate128h(const _Float16* __restrict__ Ah,
                                                     const int* __restrict__ rowptr,
                                                     const int* __restrict__ csr,
                                                     const float* __restrict__ dinv,
                                                     const float* __restrict__ bias,
                                                     float* __restrict__ Y) {
  int wid = threadIdx.x >> 6, lane = threadIdx.x & 63;
  int n = blockIdx.x * 4 + wid;  // grid 5000 -> n < 20000
  float di = dinv[n];
  half2v self = *(const half2v*)(Ah + (size_t)n * 128 + lane * 2);
  float a0 = (float)self[0] * di, a1 = (float)self[1] * di;
  int e0 = rowptr[n], m = rowptr[n + 1] - e0;
  half2v r0 = {}, r1 = {};
  float d0 = 0.f, d1 = 0.f;
  if (m > 0) {
    int s0 = csr[e0];
    r0 = *(const half2v*)(Ah + (size_t)s0 * 128 + lane * 2);
    d0 = dinv[s0];
  }
  if (m > 1) {
    int s1 = csr[e0 + 1];
    r1 = *(const half2v*)(Ah + (size_t)s1 * 128 + lane * 2);
    d1 = dinv[s1];
  }
  for (int e = 0; e < m; ++e) {
    half2v r2 = {};
    float d2 = 0.f;
    if (e + 2 < m) {
      int s2 = csr[e0 + e + 2];
      r2 = *(const half2v*)(Ah + (size_t)s2 * 128 + lane * 2);
      d2 = dinv[s2];
    }
    a0 += (float)r0[0] * d0;
    a1 += (float)r0[1] * d0;
    r0 = r1; d0 = d1; r1 = r2; d1 = d2;
  }
  float2 outv = {a0 * di + bias[lane * 2], a1 * di + bias[lane * 2 + 1]};
  *(float2*)(Y + (size_t)n * 128 + lane * 2) = outv;
}

__global__ __launch_bounds__(256) void aggregate40h(const _Float16* __restrict__ Ch,
                                                    const int* __restrict__ rowptr,
                                                    const int* __restrict__ csr,
                                                    const float* __restrict__ dinv,
                                                    const float* __restrict__ bias,
                                                    float* __restrict__ out) {
  int wid = threadIdx.x >> 6, lane = threadIdx.x & 63;
  int n = blockIdx.x * 4 + wid;
  float di = dinv[n];
  float acc = (float)Ch[(size_t)n * 64 + lane] * di;
  int e0 = rowptr[n], m = rowptr[n + 1] - e0;
  float r0 = 0.f, r1 = 0.f, d0 = 0.f, d1 = 0.f;
  if (m > 0) {
    int s0 = csr[e0];
    r0 = (float)Ch[(size_t)s0 * 64 + lane];
    d0 = dinv[s0];
  }
  if (m > 1) {
    int s1 = csr[e0 + 1];
    r1 = (float)Ch[(size_t)s1 * 64 + lane];
    d1 = dinv[s1];
  }
  for (int e = 0; e < m; ++e) {
    float r2 = 0.f, d2 = 0.f;
    if (e + 2 < m) {
      int s2 = csr[e0 + e + 2];
      r2 = (float)Ch[(size_t)s2 * 64 + lane];
      d2 = dinv[s2];
    }
    acc += r0 * d0;
    r0 = r1; d0 = d1; r1 = r2; d1 = d2;
  }
  if (lane < 40) out[(size_t)n * 40 + lane] = acc * di + bias[lane];
}

// ---------------- batchnorm stats (atomic-free partials) ----------------
#define BN_BLOCKS 64
__global__ void bn_stats(const float* __restrict__ H, double* __restrict__ partial) {
  int tid = threadIdx.x;  // 256
  int col = tid & 127;
  double s = 0.0, s2 = 0.0;
  for (size_t idx = blockIdx.x * 256 + tid; idx < (size_t)NN * 128; idx += (size_t)BN_BLOCKS * 256) {
    float v = H[idx];
    s += v;
    s2 += (double)v * (double)v;
  }
  __shared__ double sh[512];
  sh[tid] = s;
  sh[tid + 256] = s2;
  __syncthreads();
  if (tid < 128) {
    partial[(size_t)blockIdx.x * 256 + col] = sh[tid] + sh[tid + 128];
    partial[(size_t)blockIdx.x * 256 + 128 + col] = sh[tid + 256] + sh[tid + 384];
  }
}

__global__ void bn_final(const double* __restrict__ partial, const float* __restrict__ gamma,
                         const float* __restrict__ beta, float* __restrict__ ss) {
  int c = threadIdx.x;  // 128
  double s = 0.0, s2 = 0.0;
  for (int b = 0; b < BN_BLOCKS; ++b) {
    s += partial[(size_t)b * 256 + c];
    s2 += partial[(size_t)b * 256 + 128 + c];
  }
  double mean = s / (double)NN;
  double var = s2 / (double)NN - mean * mean;
  float sc = gamma[c] * rsqrtf((float)var + 1e-5f);
  ss[c] = sc;
  ss[128 + c] = beta[c] - (float)mean * sc;
}

// ---------------- launch ----------------
extern "C" void kernel_launch(void* const* d_in, const int* in_sizes, int n_in,
                              void* d_out, int out_size, void* d_ws, size_t ws_size,
                              hipStream_t stream) {
  const float* x = (const float*)d_in[0];
  const int* ei = (const int*)d_in[1];
  const float* bw0 = (const float*)d_in[2];
  const float* sw0 = (const float*)d_in[3];
  const float* b0 = (const float*)d_in[4];
  const float* bw1 = (const float*)d_in[5];
  const float* sw1 = (const float*)d_in[6];
  const float* b1 = (const float*)d_in[7];
  const float* bwo = (const float*)d_in[8];
  const float* swo = (const float*)d_in[9];
  const float* bo = (const float*)d_in[10];
  const float* gamma = (const float*)d_in[11];
  const float* beta = (const float*)d_in[12];
  const int E = in_sizes[1] / 2;
  const int* esrc = ei;
  const int* edst = ei + E;

  char* ws = (char*)d_ws;
  size_t off = 0;
  auto alloc = [&](size_t bytes) -> void* {
    void* p = ws + off;
    off = (off + bytes + 255) & ~(size_t)255;
    return p;
  };
  // +16384 halfs of pad on each weight pack for the ks+1 prefetch overrun
  _Float16* WPA0 = (_Float16*)alloc((196608 + 16384) * 2);
  _Float16* WPA1 = (_Float16*)alloc((196608 + 16384) * 2);
  _Float16* WPC = (_Float16*)alloc((65536 + 16384) * 2);
  float* dinv = (float*)alloc(NN * 4);
  int* degE = (int*)alloc(NN * 4);
  int* rowptr = (int*)alloc((NN + 1) * 4);
  int* cursor = (int*)alloc(NN * 4);
  int* csr = (int*)alloc((size_t)E * 4);
  _Float16* F = (_Float16*)alloc(((size_t)NPAD * 1024 + 64) * 2);  // 41 MB, reused 3x
  _Float16* A = (_Float16*)alloc((size_t)NPAD * 128 * 2);          // fp16 GEMM out
  float* h1 = (float*)alloc((size_t)NN * 128 * 4);                 // h2 aliases h1
  float* P0 = (float*)alloc((size_t)NPAD * 64 * 4);
  float* P1 = (float*)alloc((size_t)NPAD * 64 * 4);
  _Float16* Ch = (_Float16*)alloc((size_t)NPAD * 64 * 2);          // fp16 combined out
  double* partial = (double*)alloc((size_t)BN_BLOCKS * 256 * 8);
  float* ssb = (float*)alloc(256 * 4);
  float* h2 = h1;
  (void)ws_size; (void)n_in; (void)out_size;

  int egrid = (E + 255) / 256;
  const int GG = 626;  // 626*32 = 20032 rows

  hipMemsetAsync(degE, 0, NN * sizeof(int), stream);
  packw_all<<<1792, 256, 0, stream>>>(bw0, sw0, bw1, sw1, bwo, swo, WPA0, WPA1, WPC);
  count_deg<<<egrid, 256, 0, stream>>>(edst, degE, E);
  build_meta2<<<1, 1024, 0, stream>>>(degE, rowptr, cursor, dinv, NN);
  fill_csr<<<egrid, 256, 0, stream>>>(esrc, edst, cursor, csr, E);

  // layer 0 (+ out chunk 0)
  fb_kernel<<<10000, 256, 0, stream>>>(x, ssb, F, 0);
  gemmA4<<<GG, 512, 0, stream>>>(F, WPA0, A, P0);
  aggregate128h<<<5000, 256, 0, stream>>>(A, rowptr, csr, dinv, b0, h1);
  bn_stats<<<BN_BLOCKS, 256, 0, stream>>>(h1, partial);
  bn_final<<<1, 128, 0, stream>>>(partial, gamma, beta, ssb);

  // layer 1 (+ out chunk 1)
  fb_kernel<<<10000, 256, 0, stream>>>(h1, ssb, F, 1);
  gemmA4<<<GG, 512, 0, stream>>>(F, WPA1, A, P1);
  aggregate128h<<<5000, 256, 0, stream>>>(A, rowptr, csr, dinv, b1, h2);
  bn_stats<<<BN_BLOCKS, 256, 0, stream>>>(h2, partial);
  bn_final<<<1, 128, 0, stream>>>(partial, gamma, beta, ssb);

  // out chunk 2 + combine, then aggregate
  fb_kernel<<<10000, 256, 0, stream>>>(h2, ssb, F, 1);
  gemmC4<<<GG, 512, 0, stream>>>(F, WPC, P0, P1, Ch);
  aggregate40h<<<5000, 256, 0, stream>>>(Ch, rowptr, csr, dinv, bo, (float*)d_out);
}